// Round 9
// baseline (2326.918 us; speedup 1.0000x reference)
//
#include <hip/hip_runtime.h>
#include <math.h>

#define BB 512
#define SS 2048
#define DD 19
#define HH 40
#define CH 32
#define NCH (SS / CH)   // 64 chunks
#define XGS 33          // xg col stride [row][XGS]: addr%32=(row+t)%32 -> 2-way max
#define RS 41           // ring row stride
#define HS 48           // h buffer stride (16B aligned)

// quad_perm DPP: xor1=0xB1, xor2=0x4E, xor3=0x1B (validated R8)
#define QPERM(v, ctrl) __int_as_float(__builtin_amdgcn_mov_dpp(__float_as_int(v), (ctrl), 0xf, 0xf, true))

__device__ __forceinline__ float gate_act(float a, float mulk) {
    // mulk=1: sigmoid(a); mulk=2: tanh(a). 1 - mulk/(exp(mulk*a)+1), NaN-free.
    float e = __expf(a * mulk);
    float r = __builtin_amdgcn_rcpf(e + 1.0f);
    return fmaf(-mulk, r, 1.0f);
}
__device__ __forceinline__ float tanh_fast(float x) {
    float e = __expf(2.0f * x);
    float r = __builtin_amdgcn_rcpf(e + 1.0f);
    return fmaf(-2.0f, r, 1.0f);
}
__device__ __forceinline__ float sigm_fast(float x) {
    float e = __expf(x);
    float r = __builtin_amdgcn_rcpf(e + 1.0f);
    return fmaf(-1.0f, r, 1.0f);
}

__global__ __launch_bounds__(256, 2)  // VGPR cap 256, 2 blocks/CU
void lstm_fused(const float* __restrict__ x,
                const float* __restrict__ W_ih,
                const float* __restrict__ W_hh,
                const float* __restrict__ b_ih,
                const float* __restrict__ b_hh,
                const float* __restrict__ ln_g,
                const float* __restrict__ ln_b,
                const float* __restrict__ W1,
                const float* __restrict__ b1,
                const float* __restrict__ W2,
                const float* __restrict__ b2,
                const float* __restrict__ Wo,
                const float* __restrict__ bo,
                const float* __restrict__ log_thr,
                float* __restrict__ out) {
    __shared__ float s_xg[2][4 * HH][XGS];       // 42.2 KB, xg = x@W_ih + biases
    __shared__ float s_ring[CH][RS];             // h history; reused for r1
    __shared__ __align__(16) float s_h[2][HS];   // double-buffered current h
    __shared__ __align__(16) float s_x[2][CH][20]; // wave-3-private x staging
    __shared__ __align__(16) float s_W1[HH * HH];
    __shared__ __align__(16) float s_W2[HH * HH];
    __shared__ float s_lng[HH], s_lnb[HH], s_Wo[HH], s_b1[HH], s_b2[HH];
    __shared__ float s_part[256];

    const int tid = threadIdx.x;
    const int lane = tid & 63;
    const int wave = tid >> 6;
    const int b = blockIdx.x;

    // ---- cooperative staging of post-LSTM weights ----
    for (int i = tid; i < HH * HH; i += 256) { s_W1[i] = W1[i]; s_W2[i] = W2[i]; }
    if (tid < HH) {
        s_lng[tid] = ln_g[tid]; s_lnb[tid] = ln_b[tid]; s_Wo[tid] = Wo[tid];
        s_b1[tid] = b1[tid]; s_b2[tid] = b2[tid];
    }
    if (tid < HS) { s_h[0][tid] = 0.0f; s_h[1][tid] = 0.0f; }

    const float bo0 = bo[0];
    const float thrv = expf(log_thr[0]);

    // ---- gate thread setup: thread 4u+g owns gate row g*40+u (h-part only) ----
    const bool isGate = tid < 4 * HH;   // 160 gate threads
    const int g = tid & 3;
    const int u = tid >> 2;
    const int grow = g * HH + u;
    const float mulk = (g == 2) ? 2.0f : 1.0f;

    float whh[HH];
    if (isGate) {
        const float4* wr = (const float4*)&W_hh[grow * HH];
#pragma unroll
        for (int q = 0; q < 10; ++q) {
            float4 f = wr[q];
            whh[4*q] = f.x; whh[4*q+1] = f.y; whh[4*q+2] = f.z; whh[4*q+3] = f.w;
        }
    }
    float cc = 0.0f, hh = 0.0f;   // live in g==0 lanes

    // ---- wave 3: xg producer (rows lane, lane+64, 128+(lane&31)) ----
    float wx0[DD], wx1[DD], wx2[DD];
    float bq0 = 0.f, bq1 = 0.f, bq2 = 0.f;
    float xreg[10];
    const size_t xbase = (size_t)b * SS * DD;
    if (wave == 3) {
        const int r0 = lane, r1 = lane + 64, r2 = 128 + (lane & 31);
#pragma unroll
        for (int d = 0; d < DD; ++d) {
            wx0[d] = W_ih[r0 * DD + d];
            wx1[d] = W_ih[r1 * DD + d];
            wx2[d] = W_ih[r2 * DD + d];
        }
        bq0 = b_ih[r0] + b_hh[r0];
        bq1 = b_ih[r1] + b_hh[r1];
        bq2 = b_ih[r2] + b_hh[r2];

        // prologue: stage x(chunk 0), compute xg[0] fully, prefetch x(chunk 1)
        const float* xp = x + xbase;
#pragma unroll
        for (int q = 0; q < 10; ++q) {
            int i = lane + 64 * q;
            if (i < CH * DD) s_x[0][i / DD][i % DD] = xp[i];
        }
        asm volatile("s_waitcnt vmcnt(0) lgkmcnt(0)" ::: "memory");
#pragma unroll 1
        for (int t = 0; t < CH; ++t) {
            const float4* xr = (const float4*)&s_x[0][t][0];
            float4 f0 = xr[0], f1 = xr[1], f2 = xr[2], f3 = xr[3], f4 = xr[4];
            float xv[20];
            xv[0]=f0.x; xv[1]=f0.y; xv[2]=f0.z; xv[3]=f0.w;
            xv[4]=f1.x; xv[5]=f1.y; xv[6]=f1.z; xv[7]=f1.w;
            xv[8]=f2.x; xv[9]=f2.y; xv[10]=f2.z; xv[11]=f2.w;
            xv[12]=f3.x; xv[13]=f3.y; xv[14]=f3.z; xv[15]=f3.w;
            xv[16]=f4.x; xv[17]=f4.y; xv[18]=f4.z; xv[19]=f4.w;
            float d0a = bq0, d0b = 0.f, d1a = bq1, d1b = 0.f, d2a = bq2, d2b = 0.f;
#pragma unroll
            for (int d = 0; d < 18; d += 2) {
                d0a = fmaf(wx0[d], xv[d], d0a); d0b = fmaf(wx0[d+1], xv[d+1], d0b);
                d1a = fmaf(wx1[d], xv[d], d1a); d1b = fmaf(wx1[d+1], xv[d+1], d1b);
                d2a = fmaf(wx2[d], xv[d], d2a); d2b = fmaf(wx2[d+1], xv[d+1], d2b);
            }
            d0a = fmaf(wx0[18], xv[18], d0a);
            d1a = fmaf(wx1[18], xv[18], d1a);
            d2a = fmaf(wx2[18], xv[18], d2a);
            s_xg[0][lane][t] = d0a + d0b;
            s_xg[0][lane + 64][t] = d1a + d1b;
            if (lane < 32) s_xg[0][128 + (lane & 31)][t] = d2a + d2b;
        }
        const float* xp1 = x + xbase + CH * DD;
#pragma unroll
        for (int q = 0; q < 10; ++q) {
            int i = lane + 64 * q;
            xreg[q] = (i < CH * DD) ? xp1[i] : 0.0f;
        }
    }
    __syncthreads();   // weights + h init + xg[0] visible

    for (int ch = 0; ch < NCH; ++ch) {
        // ---- Phase A (wave-3 private, no barrier): regs -> s_x[nxt]; load ch+2 ----
        if (wave == 3 && ch + 1 < NCH) {
#pragma unroll
            for (int q = 0; q < 10; ++q) {
                int i = lane + 64 * q;
                if (i < CH * DD) s_x[(ch + 1) & 1][i / DD][i % DD] = xreg[q];
            }
            if (ch + 2 < NCH) {
                const float* xp2 = x + xbase + (size_t)(ch + 2) * CH * DD;
#pragma unroll
                for (int q = 0; q < 10; ++q) {
                    int i = lane + 64 * q;
                    xreg[q] = (i < CH * DD) ? xp2[i] : 0.0f;
                }
            }
        }

        float (*xg)[XGS] = s_xg[ch & 1];
        float (*xgN)[XGS] = s_xg[(ch + 1) & 1];
        float p = 0.0f;
        if (isGate) p = xg[grow][0];

        // ---- 32 recurrent steps; wave 3 computes next chunk's xg step-sliced ----
        for (int t = 0; t < CH; ++t) {
            if (wave == 3) {
                if (ch + 1 < NCH) {
                    const float4* xr = (const float4*)&s_x[(ch + 1) & 1][t][0];
                    float4 f0 = xr[0], f1 = xr[1], f2 = xr[2], f3 = xr[3], f4 = xr[4];
                    float xv[20];
                    xv[0]=f0.x; xv[1]=f0.y; xv[2]=f0.z; xv[3]=f0.w;
                    xv[4]=f1.x; xv[5]=f1.y; xv[6]=f1.z; xv[7]=f1.w;
                    xv[8]=f2.x; xv[9]=f2.y; xv[10]=f2.z; xv[11]=f2.w;
                    xv[12]=f3.x; xv[13]=f3.y; xv[14]=f3.z; xv[15]=f3.w;
                    xv[16]=f4.x; xv[17]=f4.y; xv[18]=f4.z; xv[19]=f4.w;
                    float d0a = bq0, d0b = 0.f, d1a = bq1, d1b = 0.f, d2a = bq2, d2b = 0.f;
#pragma unroll
                    for (int d = 0; d < 18; d += 2) {
                        d0a = fmaf(wx0[d], xv[d], d0a); d0b = fmaf(wx0[d+1], xv[d+1], d0b);
                        d1a = fmaf(wx1[d], xv[d], d1a); d1b = fmaf(wx1[d+1], xv[d+1], d1b);
                        d2a = fmaf(wx2[d], xv[d], d2a); d2b = fmaf(wx2[d+1], xv[d+1], d2b);
                    }
                    d0a = fmaf(wx0[18], xv[18], d0a);
                    d1a = fmaf(wx1[18], xv[18], d1a);
                    d2a = fmaf(wx2[18], xv[18], d2a);
                    xgN[lane][t] = d0a + d0b;
                    xgN[lane + 64][t] = d1a + d1b;
                    if (lane < 32) xgN[128 + (lane & 31)][t] = d2a + d2b;
                }
            } else if (isGate) {
                const float4* h4 = (const float4*)s_h[t & 1];
                float a0 = p, a1 = 0.f, a2 = 0.f, a3 = 0.f;
#pragma unroll
                for (int q = 0; q < 10; ++q) {
                    float4 f = h4[q];
                    a0 = fmaf(f.x, whh[4*q+0], a0);
                    a1 = fmaf(f.y, whh[4*q+1], a1);
                    a2 = fmaf(f.z, whh[4*q+2], a2);
                    a3 = fmaf(f.w, whh[4*q+3], a3);
                }
                if (t + 1 < CH) p = xg[grow][t + 1];   // prefetch (off-chain)
                float acc = (a0 + a1) + (a2 + a3);
                float av = gate_act(acc, mulk);
                float bv = QPERM(av, 0xB1), cv = QPERM(av, 0x4E), dv = QPERM(av, 0x1B);
                // lane 4u+0: av=i, bv=f, cv=g~, dv=o
                if (g == 0) {
                    cc = fmaf(bv, cc, av * cv);
                    hh = dv * tanh_fast(cc);
                    s_h[(t + 1) & 1][u] = hh;
                    s_ring[t][u] = hh;
                }
            }
            __syncthreads();
        }

        // ---- consume chunk: LN + MLP + head (8 threads/step x 5 rows) ----
        {
            const int st = tid & 31;
            const int q8 = tid >> 5;   // 0..7
            float hv[HH];
#pragma unroll
            for (int k = 0; k < HH; ++k) hv[k] = s_ring[st][k];
            float m0 = 0.f, m1 = 0.f, q0 = 0.f, q1 = 0.f;
#pragma unroll
            for (int k = 0; k < HH; k += 2) {
                m0 += hv[k]; m1 += hv[k + 1];
                q0 = fmaf(hv[k], hv[k], q0); q1 = fmaf(hv[k + 1], hv[k + 1], q1);
            }
            float mu = (m0 + m1) * (1.0f / HH);
            float var = (q0 + q1) * (1.0f / HH) - mu * mu;
            float inv = 1.0f / sqrtf(var + 1e-5f);
#pragma unroll
            for (int k = 0; k < HH; ++k)
                hv[k] = fmaf((hv[k] - mu) * inv, s_lng[k], s_lnb[k]);  // hv := ln
            // sigWo: STATIC full loop (rule #20), kept only by q8==0
            float part = 0.f;
#pragma unroll
            for (int k = 0; k < HH; ++k)
                part = fmaf(sigm_fast(hv[k]), s_Wo[k], part);
            if (q8 != 0) part = 0.f;
            __syncthreads();   // all ring reads done -> reuse ring for r1
            float r1v[5];
#pragma unroll
            for (int jj = 0; jj < 5; ++jj) {
                int j = q8 * 5 + jj;
                const float4* wr = (const float4*)&s_W1[j * HH];
                float a0 = s_b1[j], a1 = 0.f;
#pragma unroll
                for (int q = 0; q < 10; ++q) {
                    float4 w4 = wr[q];
                    a0 = fmaf(w4.x, hv[4*q+0], a0); a1 = fmaf(w4.y, hv[4*q+1], a1);
                    a0 = fmaf(w4.z, hv[4*q+2], a0); a1 = fmaf(w4.w, hv[4*q+3], a1);
                }
                r1v[jj] = tanh_fast(a0 + a1);
                s_ring[st][j] = r1v[jj];
            }
            __syncthreads();
            float rr[HH];
#pragma unroll
            for (int k = 0; k < HH; ++k) rr[k] = s_ring[st][k];
#pragma unroll
            for (int jj = 0; jj < 5; ++jj) {
                int j = q8 * 5 + jj;
                const float4* wr = (const float4*)&s_W2[j * HH];
                float a0 = s_b2[j], a1 = 0.f;
#pragma unroll
                for (int q = 0; q < 10; ++q) {
                    float4 w4 = wr[q];
                    a0 = fmaf(w4.x, rr[4*q+0], a0); a1 = fmaf(w4.y, rr[4*q+1], a1);
                    a0 = fmaf(w4.z, rr[4*q+2], a0); a1 = fmaf(w4.w, rr[4*q+3], a1);
                }
                float r2 = tanh_fast(a0 + a1);
                part = fmaf(r2, s_Wo[j], part);
            }
            s_part[tid] = part;
            __syncthreads();
            if (tid < CH) {
                float tot = bo0;
#pragma unroll
                for (int qq = 0; qq < 8; ++qq) tot += s_part[tid + 32 * qq];
                float raw = tanh_fast(tot);
                float sg = (fabsf(raw) >= thrv) ? raw : 0.0f;
                out[(size_t)b * SS + (size_t)ch * CH + tid] = sg;
            }
        }
    }

    // ---- final states + threshold scalar ----
    if (isGate && g == 0) {
        out[(size_t)BB * SS + (size_t)b * HH + u] = hh;
        out[(size_t)BB * SS + (size_t)BB * HH + (size_t)b * HH + u] = cc;
    }
    if (b == 0 && tid == 0) {
        out[(size_t)BB * SS + 2 * (size_t)BB * HH] = thrv;
    }
}

extern "C" void kernel_launch(void* const* d_in, const int* in_sizes, int n_in,
                              void* d_out, int out_size, void* d_ws, size_t ws_size,
                              hipStream_t stream) {
    const float* x    = (const float*)d_in[0];
    const float* W_ih = (const float*)d_in[1];
    const float* W_hh = (const float*)d_in[2];
    const float* b_ih = (const float*)d_in[3];
    const float* b_hh = (const float*)d_in[4];
    const float* ln_g = (const float*)d_in[5];
    const float* ln_b = (const float*)d_in[6];
    const float* W1   = (const float*)d_in[7];
    const float* b1   = (const float*)d_in[8];
    const float* W2   = (const float*)d_in[9];
    const float* b2   = (const float*)d_in[10];
    const float* Wo   = (const float*)d_in[11];
    const float* bo   = (const float*)d_in[12];
    const float* lt   = (const float*)d_in[13];
    float* out = (float*)d_out;

    lstm_fused<<<dim3(BB), dim3(256), 0, stream>>>(
        x, W_ih, W_hh, b_ih, b_hh, ln_g, ln_b, W1, b1, W2, b2, Wo, bo, lt, out);
}

// Round 10
// 2030.804 us; speedup vs baseline: 1.1458x; 1.1458x over previous
//
#include <hip/hip_runtime.h>
#include <math.h>

#define BB 512
#define SS 2048
#define DD 19
#define HH 40
#define CH 32
#define NCH (SS / CH)   // 64 chunks
#define RS 41           // ring row stride ([t][RS])
#define HS 48           // h buffer stride (16B aligned)

// quad_perm DPP: xor1=0xB1, xor2=0x4E, xor3=0x1B
#define QPERM(v, ctrl) __int_as_float(__builtin_amdgcn_mov_dpp(__float_as_int(v), (ctrl), 0xf, 0xf, true))

__device__ __forceinline__ float gate_act(float a, float mulk) {
    float e = __expf(a * mulk);
    float r = __builtin_amdgcn_rcpf(e + 1.0f);
    return fmaf(-mulk, r, 1.0f);
}
__device__ __forceinline__ float tanh_fast(float x) {
    float e = __expf(2.0f * x);
    float r = __builtin_amdgcn_rcpf(e + 1.0f);
    return fmaf(-2.0f, r, 1.0f);
}
__device__ __forceinline__ float sigm_fast(float x) {
    float e = __expf(x);
    float r = __builtin_amdgcn_rcpf(e + 1.0f);
    return fmaf(-1.0f, r, 1.0f);
}

__global__ __launch_bounds__(256, 2)  // VGPR cap 256 (no spill), 2 blocks/CU
void lstm_fused(const float* __restrict__ x,
                const float* __restrict__ W_ih,
                const float* __restrict__ W_hh,
                const float* __restrict__ b_ih,
                const float* __restrict__ b_hh,
                const float* __restrict__ ln_g,
                const float* __restrict__ ln_b,
                const float* __restrict__ W1,
                const float* __restrict__ b1,
                const float* __restrict__ W2,
                const float* __restrict__ b2,
                const float* __restrict__ Wo,
                const float* __restrict__ bo,
                const float* __restrict__ log_thr,
                float* __restrict__ out) {
    __shared__ float s_ring[CH][RS];             // h history; reused for r1
    __shared__ __align__(16) float s_h[2][HS];   // double-buffered current h
    __shared__ __align__(16) float s_x[CH][20];  // staged x chunk (19 + 1 pad)
    __shared__ __align__(16) float s_W1[HH * HH];
    __shared__ __align__(16) float s_W2[HH * HH];
    __shared__ float s_lng[HH], s_lnb[HH], s_Wo[HH], s_b1[HH], s_b2[HH];
    __shared__ float s_part[256];

    const int tid = threadIdx.x;
    const int b = blockIdx.x;

    for (int i = tid; i < HH * HH; i += 256) { s_W1[i] = W1[i]; s_W2[i] = W2[i]; }
    if (tid < HH) {
        s_lng[tid] = ln_g[tid]; s_lnb[tid] = ln_b[tid]; s_Wo[tid] = Wo[tid];
        s_b1[tid] = b1[tid]; s_b2[tid] = b2[tid];
    }
    if (tid < HS) { s_h[0][tid] = 0.0f; s_h[1][tid] = 0.0f; }

    const float bo0 = bo[0];
    const float thrv = expf(log_thr[0]);

    const bool isGate = tid < 4 * HH;
    const int g = tid & 3;
    const int u = tid >> 2;
    const int grow = g * HH + u;
    const float mulk = (g == 2) ? 2.0f : 1.0f;

    float wih[DD];
    float whh[HH];
    float bsum = 0.0f;
    if (isGate) {
#pragma unroll
        for (int d = 0; d < DD; ++d) wih[d] = W_ih[grow * DD + d];
        const float4* wr = (const float4*)&W_hh[grow * HH];
#pragma unroll
        for (int q = 0; q < 10; ++q) {
            float4 f = wr[q];
            whh[4*q] = f.x; whh[4*q+1] = f.y; whh[4*q+2] = f.z; whh[4*q+3] = f.w;
        }
        bsum = b_ih[grow] + b_hh[grow];
    }
    float cc = 0.0f, hh = 0.0f;

    const int i0 = tid, i1 = tid + 256, i2 = tid + 512;
    const int st0 = i0 / DD, d0 = i0 % DD;
    const int st1 = i1 / DD, d1 = i1 % DD;
    const int st2 = i2 / DD, d2 = i2 % DD;
    float xr0 = 0.f, xr1 = 0.f, xr2 = 0.f;
    {
        const float* xp = x + (size_t)b * SS * DD;
        xr0 = xp[i0];
        xr1 = xp[i1];
        if (i2 < CH * DD) xr2 = xp[i2];
    }

    __syncthreads();

    for (int ch = 0; ch < NCH; ++ch) {
        s_x[st0][d0] = xr0;
        s_x[st1][d1] = xr1;
        if (i2 < CH * DD) s_x[st2][d2] = xr2;
        if (ch + 1 < NCH) {
            const float* xp = x + ((size_t)b * SS + (size_t)(ch + 1) * CH) * DD;
            xr0 = xp[i0];
            xr1 = xp[i1];
            if (i2 < CH * DD) xr2 = xp[i2];
        }
        __syncthreads();

        for (int t = 0; t < CH; ++t) {
            if (isGate) {
                const float4* h4 = (const float4*)s_h[t & 1];
                const float4* x4 = (const float4*)&s_x[t][0];
                float a0 = bsum, a1 = 0.f, a2 = 0.f, a3 = 0.f;
                float4 xa = x4[0], xb = x4[1], xc = x4[2], xd = x4[3], xe = x4[4];
                a0 = fmaf(xa.x, wih[0], a0);  a1 = fmaf(xa.y, wih[1], a1);
                a2 = fmaf(xa.z, wih[2], a2);  a3 = fmaf(xa.w, wih[3], a3);
                a0 = fmaf(xb.x, wih[4], a0);  a1 = fmaf(xb.y, wih[5], a1);
                a2 = fmaf(xb.z, wih[6], a2);  a3 = fmaf(xb.w, wih[7], a3);
                a0 = fmaf(xc.x, wih[8], a0);  a1 = fmaf(xc.y, wih[9], a1);
                a2 = fmaf(xc.z, wih[10], a2); a3 = fmaf(xc.w, wih[11], a3);
                a0 = fmaf(xd.x, wih[12], a0); a1 = fmaf(xd.y, wih[13], a1);
                a2 = fmaf(xd.z, wih[14], a2); a3 = fmaf(xd.w, wih[15], a3);
                a0 = fmaf(xe.x, wih[16], a0); a1 = fmaf(xe.y, wih[17], a1);
                a2 = fmaf(xe.z, wih[18], a2);
#pragma unroll
                for (int q = 0; q < 10; ++q) {
                    float4 f = h4[q];
                    a0 = fmaf(f.x, whh[4*q+0], a0);
                    a1 = fmaf(f.y, whh[4*q+1], a1);
                    a2 = fmaf(f.z, whh[4*q+2], a2);
                    a3 = fmaf(f.w, whh[4*q+3], a3);
                }
                float acc = (a0 + a1) + (a2 + a3);
                float av = gate_act(acc, mulk);
                float bv = __shfl_xor(av, 1);
                float cv = __shfl_xor(av, 2);
                float dv = __shfl_xor(bv, 2);
                if (g == 0) {
                    cc = fmaf(bv, cc, av * cv);
                    hh = dv * tanh_fast(cc);
                    s_h[(t + 1) & 1][u] = hh;
                    s_ring[t][u] = hh;
                }
            }
            __syncthreads();
        }

        {
            const int st = tid & 31;
            const int q8 = tid >> 5;
            float hv[HH];
#pragma unroll
            for (int k = 0; k < HH; ++k) hv[k] = s_ring[st][k];
            float m0 = 0.f, m1 = 0.f, q0 = 0.f, q1 = 0.f;
#pragma unroll
            for (int k = 0; k < HH; k += 2) {
                m0 += hv[k]; m1 += hv[k + 1];
                q0 = fmaf(hv[k], hv[k], q0); q1 = fmaf(hv[k + 1], hv[k + 1], q1);
            }
            float mu = (m0 + m1) * (1.0f / HH);
            float var = (q0 + q1) * (1.0f / HH) - mu * mu;
            float inv = 1.0f / sqrtf(var + 1e-5f);
#pragma unroll
            for (int k = 0; k < HH; ++k)
                hv[k] = fmaf((hv[k] - mu) * inv, s_lng[k], s_lnb[k]);
            float part = 0.f;
#pragma unroll
            for (int k = 0; k < HH; ++k)
                part = fmaf(sigm_fast(hv[k]), s_Wo[k], part);
            if (q8 != 0) part = 0.f;
            __syncthreads();
            float r1v[5];
#pragma unroll
            for (int jj = 0; jj < 5; ++jj) {
                int j = q8 * 5 + jj;
                const float4* wr = (const float4*)&s_W1[j * HH];
                float a0 = s_b1[j], a1 = 0.f;
#pragma unroll
                for (int q = 0; q < 10; ++q) {
                    float4 w4 = wr[q];
                    a0 = fmaf(w4.x, hv[4*q+0], a0); a1 = fmaf(w4.y, hv[4*q+1], a1);
                    a0 = fmaf(w4.z, hv[4*q+2], a0); a1 = fmaf(w4.w, hv[4*q+3], a1);
                }
                r1v[jj] = tanh_fast(a0 + a1);
                s_ring[st][j] = r1v[jj];
            }
            __syncthreads();
            float rr[HH];
#pragma unroll
            for (int k = 0; k < HH; ++k) rr[k] = s_ring[st][k];
#pragma unroll
            for (int jj = 0; jj < 5; ++jj) {
                int j = q8 * 5 + jj;
                const float4* wr = (const float4*)&s_W2[j * HH];
                float a0 = s_b2[j], a1 = 0.f;
#pragma unroll
                for (int q = 0; q < 10; ++q) {
                    float4 w4 = wr[q];
                    a0 = fmaf(w4.x, rr[4*q+0], a0); a1 = fmaf(w4.y, rr[4*q+1], a1);
                    a0 = fmaf(w4.z, rr[4*q+2], a0); a1 = fmaf(w4.w, rr[4*q+3], a1);
                }
                float r2 = tanh_fast(a0 + a1);
                part = fmaf(r2, s_Wo[j], part);
            }
            s_part[tid] = part;
            __syncthreads();
            if (tid < CH) {
                float tot = bo0;
#pragma unroll
                for (int qq = 0; qq < 8; ++qq) tot += s_part[tid + 32 * qq];
                float raw = tanh_fast(tot);
                float sg = (fabsf(raw) >= thrv) ? raw : 0.0f;
                out[(size_t)b * SS + (size_t)ch * CH + tid] = sg;
            }
        }
    }

    if (isGate && g == 0) {
        out[(size_t)BB * SS + (size_t)b * HH + u] = hh;
        out[(size_t)BB * SS + (size_t)BB * HH + (size_t)b * HH + u] = cc;
    }
    if (b == 0 && tid == 0) {
        out[(size_t)BB * SS + 2 * (size_t)BB * HH] = thrv;
    }
}

// ---------------- DIAGNOSTIC PROBE: bare recurrence, produce-only ----------------
// Mirrors the main kernel's per-step machinery exactly (LDS h round-trip, dummy
// xg LDS read, gate dot issue count, act chain, shfl combine, 1 barrier/step)
// with NO x-staging, NO xg compute, NO consume. probe_dur = dur_total - dur_main.
__global__ __launch_bounds__(256, 2) void probe_rec(float* __restrict__ ws) {
    __shared__ __align__(16) float s_h[2][HS];
    __shared__ float s_ring[CH][RS];
    __shared__ float s_xgd[4 * HH];

    const int tid = threadIdx.x;
    if (tid < HS) { s_h[0][tid] = 0.0f; s_h[1][tid] = 0.0f; }
    if (tid < 4 * HH) s_xgd[tid] = 0.001f * (float)tid;

    const bool isGate = tid < 4 * HH;
    const int g = tid & 3;
    const int u = tid >> 2;
    const float mulk = (g == 2) ? 2.0f : 1.0f;

    float wih[DD];   // mirrors x-part FMAs (operands synthetic, in-register)
    float whh[HH];
#pragma unroll
    for (int d = 0; d < DD; ++d) wih[d] = 0.01f * (float)((tid * 5 + d * 11) & 31) - 0.15f;
#pragma unroll
    for (int k = 0; k < HH; ++k) whh[k] = 0.01f * (float)((tid * 7 + k * 13) & 31) - 0.15f;

    float cc = 0.0f, hh = 0.0f;
    float xv = 0.3f;
    __syncthreads();

    for (int t = 0; t < SS; ++t) {
        if (isGate) {
            float a0, a1 = 0.f, a2 = 0.f, a3 = 0.f;
            a0 = s_xgd[(tid + t) & 127];   // dummy xg LDS read (chain head, like main)
            // x-part stand-in: 19 FMAs on a register operand
            a0 = fmaf(xv, wih[0], a0);  a1 = fmaf(xv, wih[1], a1);
            a2 = fmaf(xv, wih[2], a2);  a3 = fmaf(xv, wih[3], a3);
            a0 = fmaf(xv, wih[4], a0);  a1 = fmaf(xv, wih[5], a1);
            a2 = fmaf(xv, wih[6], a2);  a3 = fmaf(xv, wih[7], a3);
            a0 = fmaf(xv, wih[8], a0);  a1 = fmaf(xv, wih[9], a1);
            a2 = fmaf(xv, wih[10], a2); a3 = fmaf(xv, wih[11], a3);
            a0 = fmaf(xv, wih[12], a0); a1 = fmaf(xv, wih[13], a1);
            a2 = fmaf(xv, wih[14], a2); a3 = fmaf(xv, wih[15], a3);
            a0 = fmaf(xv, wih[16], a0); a1 = fmaf(xv, wih[17], a1);
            a2 = fmaf(xv, wih[18], a2);
            // h-part: 10x b128 LDS broadcast + 40 FMAs (the real chain)
            const float4* h4 = (const float4*)s_h[t & 1];
#pragma unroll
            for (int q = 0; q < 10; ++q) {
                float4 f = h4[q];
                a0 = fmaf(f.x, whh[4*q+0], a0);
                a1 = fmaf(f.y, whh[4*q+1], a1);
                a2 = fmaf(f.z, whh[4*q+2], a2);
                a3 = fmaf(f.w, whh[4*q+3], a3);
            }
            float acc = (a0 + a1) + (a2 + a3);
            float av = gate_act(acc, mulk);
            float bv = __shfl_xor(av, 1);
            float cv = __shfl_xor(av, 2);
            float dv = __shfl_xor(bv, 2);
            if (g == 0) {
                cc = fmaf(bv, cc, av * cv);
                hh = dv * tanh_fast(cc);
                s_h[(t + 1) & 1][u] = hh;
                s_ring[t & (CH - 1)][u] = hh;
            }
        }
        __syncthreads();
    }

    if (isGate && g == 0) ws[(size_t)blockIdx.x * 64 + u] = hh + cc;
    if (tid == 192) ws[(size_t)blockIdx.x * 64 + 40 + (tid & 7)] = s_ring[0][0];
}

extern "C" void kernel_launch(void* const* d_in, const int* in_sizes, int n_in,
                              void* d_out, int out_size, void* d_ws, size_t ws_size,
                              hipStream_t stream) {
    const float* x    = (const float*)d_in[0];
    const float* W_ih = (const float*)d_in[1];
    const float* W_hh = (const float*)d_in[2];
    const float* b_ih = (const float*)d_in[3];
    const float* b_hh = (const float*)d_in[4];
    const float* ln_g = (const float*)d_in[5];
    const float* ln_b = (const float*)d_in[6];
    const float* W1   = (const float*)d_in[7];
    const float* b1   = (const float*)d_in[8];
    const float* W2   = (const float*)d_in[9];
    const float* b2   = (const float*)d_in[10];
    const float* Wo   = (const float*)d_in[11];
    const float* bo   = (const float*)d_in[12];
    const float* lt   = (const float*)d_in[13];
    float* out = (float*)d_out;

    lstm_fused<<<dim3(BB), dim3(256), 0, stream>>>(
        x, W_ih, W_hh, b_ih, b_hh, ln_g, ln_b, W1, b1, W2, b2, Wo, bo, lt, out);

    // Diagnostic probe (timed together with main; dur_probe = total - main row).
    if (ws_size >= (size_t)BB * 64 * sizeof(float)) {
        probe_rec<<<dim3(BB), dim3(256), 0, stream>>>((float*)d_ws);
    }
}

// Round 11
// 1115.721 us; speedup vs baseline: 2.0856x; 1.8202x over previous
//
#include <hip/hip_runtime.h>
#include <math.h>

#define BB 512
#define SS 2048
#define DD 19
#define HH 40
#define CH 32
#define NCH (SS / CH)   // 64 chunks
#define RS 41
#define HS 48

// quad_perm DPP: xor1=0xB1, xor2=0x4E, xor3=0x1B (validated R8)
#define QPERM(v, ctrl) __int_as_float(__builtin_amdgcn_mov_dpp(__float_as_int(v), (ctrl), 0xf, 0xf, true))

__device__ __forceinline__ float gate_act(float a, float mulk) {
    float e = __expf(a * mulk);
    float r = __builtin_amdgcn_rcpf(e + 1.0f);
    return fmaf(-mulk, r, 1.0f);
}
__device__ __forceinline__ float tanh_fast(float x) {
    float e = __expf(2.0f * x);
    float r = __builtin_amdgcn_rcpf(e + 1.0f);
    return fmaf(-2.0f, r, 1.0f);
}
__device__ __forceinline__ float sigm_fast(float x) {
    float e = __expf(x);
    float r = __builtin_amdgcn_rcpf(e + 1.0f);
    return fmaf(-1.0f, r, 1.0f);
}

// ================= Kernel 1: recurrence only, h history -> global =================
__global__ __launch_bounds__(192, 2)  // 3 waves, VGPR cap 256
void lstm_seq(const float* __restrict__ x,
              const float* __restrict__ W_ih,
              const float* __restrict__ W_hh,
              const float* __restrict__ b_ih,
              const float* __restrict__ b_hh,
              const float* __restrict__ log_thr,
              float* __restrict__ hist,
              float* __restrict__ out) {
    __shared__ __align__(16) float s_h[2][HS];
    __shared__ __align__(16) float s_x[CH][20];

    const int tid = threadIdx.x;
    const int b = blockIdx.x;
    if (tid < HS) { s_h[0][tid] = 0.0f; s_h[1][tid] = 0.0f; }

    const bool isGate = tid < 4 * HH;   // 160 gate threads
    const int g = tid & 3;
    const int u = tid >> 2;
    const int grow = g * HH + u;
    const float mulk = (g == 2) ? 2.0f : 1.0f;

    float wih[DD];
    float whh[HH];
    float bsum = 0.0f;
    if (isGate) {
#pragma unroll
        for (int d = 0; d < DD; ++d) wih[d] = W_ih[grow * DD + d];
        const float4* wr = (const float4*)&W_hh[grow * HH];
#pragma unroll
        for (int q = 0; q < 10; ++q) {
            float4 f = wr[q];
            whh[4*q] = f.x; whh[4*q+1] = f.y; whh[4*q+2] = f.z; whh[4*q+3] = f.w;
        }
        bsum = b_ih[grow] + b_hh[grow];
    }
    float cc = 0.0f, hh = 0.0f;

    // x prefetch: 608 floats / 192 threads -> 4 regs
    const int i0 = tid, i1 = tid + 192, i2 = tid + 384, i3 = tid + 576;
    const int st0 = i0 / DD, d0 = i0 % DD;
    const int st1 = i1 / DD, d1 = i1 % DD;
    const int st2 = i2 / DD, d2 = i2 % DD;
    const int st3 = i3 / DD, d3 = i3 % DD;
    const bool has3 = (i3 < CH * DD);
    float xr0, xr1, xr2, xr3 = 0.f;
    {
        const float* xp = x + (size_t)b * SS * DD;
        xr0 = xp[i0]; xr1 = xp[i1]; xr2 = xp[i2];
        if (has3) xr3 = xp[i3];
    }

    float* hb = hist + (size_t)b * SS * HH;
    __syncthreads();

    for (int ch = 0; ch < NCH; ++ch) {
        s_x[st0][d0] = xr0; s_x[st1][d1] = xr1; s_x[st2][d2] = xr2;
        if (has3) s_x[st3][d3] = xr3;
        if (ch + 1 < NCH) {
            const float* xp = x + ((size_t)b * SS + (size_t)(ch + 1) * CH) * DD;
            xr0 = xp[i0]; xr1 = xp[i1]; xr2 = xp[i2];
            if (has3) xr3 = xp[i3];
        }
        __syncthreads();

        // xpart for t=0 (bsum folded)
        float xpart = 0.0f;
        if (isGate) {
            const float4* x4 = (const float4*)&s_x[0][0];
            float4 xa = x4[0], xb = x4[1], xc = x4[2], xd = x4[3], xe = x4[4];
            float p0 = bsum, p1 = 0.f, p2 = 0.f, p3 = 0.f;
            p0 = fmaf(xa.x, wih[0], p0);  p1 = fmaf(xa.y, wih[1], p1);
            p2 = fmaf(xa.z, wih[2], p2);  p3 = fmaf(xa.w, wih[3], p3);
            p0 = fmaf(xb.x, wih[4], p0);  p1 = fmaf(xb.y, wih[5], p1);
            p2 = fmaf(xb.z, wih[6], p2);  p3 = fmaf(xb.w, wih[7], p3);
            p0 = fmaf(xc.x, wih[8], p0);  p1 = fmaf(xc.y, wih[9], p1);
            p2 = fmaf(xc.z, wih[10], p2); p3 = fmaf(xc.w, wih[11], p3);
            p0 = fmaf(xd.x, wih[12], p0); p1 = fmaf(xd.y, wih[13], p1);
            p2 = fmaf(xd.z, wih[14], p2); p3 = fmaf(xd.w, wih[15], p3);
            p0 = fmaf(xe.x, wih[16], p0); p1 = fmaf(xe.y, wih[17], p1);
            p2 = fmaf(xe.z, wih[18], p2);
            xpart = (p0 + p1) + (p2 + p3);
        }

        for (int t = 0; t < CH; ++t) {
            if (isGate) {
                // post-barrier critical region: 10 h-reads + 40 FMA only
                const float4* h4 = (const float4*)s_h[t & 1];
                float a0 = xpart, a1 = 0.f, a2 = 0.f, a3 = 0.f;
#pragma unroll
                for (int q = 0; q < 10; ++q) {
                    float4 f = h4[q];
                    a0 = fmaf(f.x, whh[4*q+0], a0);
                    a1 = fmaf(f.y, whh[4*q+1], a1);
                    a2 = fmaf(f.z, whh[4*q+2], a2);
                    a3 = fmaf(f.w, whh[4*q+3], a3);
                }
                float acc = (a0 + a1) + (a2 + a3);
                float av = gate_act(acc, mulk);
                float bv = QPERM(av, 0xB1), cv = QPERM(av, 0x4E), dv = QPERM(av, 0x1B);
                if (g == 0) {
                    cc = fmaf(bv, cc, av * cv);
                    hh = dv * tanh_fast(cc);
                    s_h[(t + 1) & 1][u] = hh;
                    hb[(size_t)(ch * CH + t) * HH + u] = hh;   // fire-and-forget
                }
                if (t + 1 < CH) {   // off-chain: xpart for t+1, pre-barrier
                    const float4* x4 = (const float4*)&s_x[t + 1][0];
                    float4 xa = x4[0], xb = x4[1], xc = x4[2], xd = x4[3], xe = x4[4];
                    float p0 = bsum, p1 = 0.f, p2 = 0.f, p3 = 0.f;
                    p0 = fmaf(xa.x, wih[0], p0);  p1 = fmaf(xa.y, wih[1], p1);
                    p2 = fmaf(xa.z, wih[2], p2);  p3 = fmaf(xa.w, wih[3], p3);
                    p0 = fmaf(xb.x, wih[4], p0);  p1 = fmaf(xb.y, wih[5], p1);
                    p2 = fmaf(xb.z, wih[6], p2);  p3 = fmaf(xb.w, wih[7], p3);
                    p0 = fmaf(xc.x, wih[8], p0);  p1 = fmaf(xc.y, wih[9], p1);
                    p2 = fmaf(xc.z, wih[10], p2); p3 = fmaf(xc.w, wih[11], p3);
                    p0 = fmaf(xd.x, wih[12], p0); p1 = fmaf(xd.y, wih[13], p1);
                    p2 = fmaf(xd.z, wih[14], p2); p3 = fmaf(xd.w, wih[15], p3);
                    p0 = fmaf(xe.x, wih[16], p0); p1 = fmaf(xe.y, wih[17], p1);
                    p2 = fmaf(xe.z, wih[18], p2);
                    xpart = (p0 + p1) + (p2 + p3);
                }
            }
            __syncthreads();
        }
    }

    if (isGate && g == 0) {
        out[(size_t)BB * SS + (size_t)b * HH + u] = hh;
        out[(size_t)BB * SS + (size_t)BB * HH + (size_t)b * HH + u] = cc;
    }
    if (b == 0 && tid == 0) {
        out[(size_t)BB * SS + 2 * (size_t)BB * HH] = expf(log_thr[0]);
    }
}

// ================= Kernel 2: LN + MLP + head, massively parallel =================
__global__ __launch_bounds__(256, 2)
void post_mlp(const float* __restrict__ hist,
              const float* __restrict__ ln_g,
              const float* __restrict__ ln_b,
              const float* __restrict__ W1,
              const float* __restrict__ b1,
              const float* __restrict__ W2,
              const float* __restrict__ b2,
              const float* __restrict__ Wo,
              const float* __restrict__ bo,
              const float* __restrict__ log_thr,
              float* __restrict__ out) {
    __shared__ float s_rows[256][HH + 1];     // 42 KB; also reused for r1 (own row)
    __shared__ __align__(16) float s_W1[HH * HH];
    __shared__ __align__(16) float s_W2[HH * HH];
    __shared__ float s_lng[HH], s_lnb[HH], s_Wo[HH], s_b1[HH], s_b2[HH];

    const int tid = threadIdx.x;
    const size_t base = (size_t)blockIdx.x * 256 * HH;

    for (int i = tid; i < HH * HH; i += 256) { s_W1[i] = W1[i]; s_W2[i] = W2[i]; }
    if (tid < HH) {
        s_lng[tid] = ln_g[tid]; s_lnb[tid] = ln_b[tid]; s_Wo[tid] = Wo[tid];
        s_b1[tid] = b1[tid]; s_b2[tid] = b2[tid];
    }
    for (int i = tid; i < 256 * HH; i += 256)   // coalesced h row staging
        s_rows[i / HH][i % HH] = hist[base + i];
    __syncthreads();

    const float bo0 = bo[0];
    const float thrv = expf(log_thr[0]);

    float hv[HH];
#pragma unroll
    for (int k = 0; k < HH; ++k) hv[k] = s_rows[tid][k];
    float m0 = 0.f, m1 = 0.f, q0 = 0.f, q1 = 0.f;
#pragma unroll
    for (int k = 0; k < HH; k += 2) {
        m0 += hv[k]; m1 += hv[k + 1];
        q0 = fmaf(hv[k], hv[k], q0); q1 = fmaf(hv[k + 1], hv[k + 1], q1);
    }
    float mu = (m0 + m1) * (1.0f / HH);
    float var = (q0 + q1) * (1.0f / HH) - mu * mu;
    float inv = 1.0f / sqrtf(var + 1e-5f);
#pragma unroll
    for (int k = 0; k < HH; ++k)
        hv[k] = fmaf((hv[k] - mu) * inv, s_lng[k], s_lnb[k]);   // hv := ln

    float part = 0.f;
#pragma unroll
    for (int k = 0; k < HH; ++k)
        part = fmaf(sigm_fast(hv[k]), s_Wo[k], part);

    // MLP1: thread owns its whole row; r1 bounced via own LDS row (no barrier)
#pragma unroll 2
    for (int j = 0; j < HH; ++j) {
        const float4* wr = (const float4*)&s_W1[j * HH];
        float a0 = s_b1[j], a1 = 0.f;
#pragma unroll
        for (int q = 0; q < 10; ++q) {
            float4 w4 = wr[q];
            a0 = fmaf(w4.x, hv[4*q+0], a0); a1 = fmaf(w4.y, hv[4*q+1], a1);
            a0 = fmaf(w4.z, hv[4*q+2], a0); a1 = fmaf(w4.w, hv[4*q+3], a1);
        }
        s_rows[tid][j] = tanh_fast(a0 + a1);
    }
    float rr[HH];
#pragma unroll
    for (int k = 0; k < HH; ++k) rr[k] = s_rows[tid][k];
#pragma unroll 2
    for (int j = 0; j < HH; ++j) {
        const float4* wr = (const float4*)&s_W2[j * HH];
        float a0 = s_b2[j], a1 = 0.f;
#pragma unroll
        for (int q = 0; q < 10; ++q) {
            float4 w4 = wr[q];
            a0 = fmaf(w4.x, rr[4*q+0], a0); a1 = fmaf(w4.y, rr[4*q+1], a1);
            a0 = fmaf(w4.z, rr[4*q+2], a0); a1 = fmaf(w4.w, rr[4*q+3], a1);
        }
        float r2 = tanh_fast(a0 + a1);
        part = fmaf(r2, s_Wo[j], part);
    }
    float raw = tanh_fast(part + bo0);
    float sg = (fabsf(raw) >= thrv) ? raw : 0.0f;
    out[(size_t)blockIdx.x * 256 + tid] = sg;
}

// ================= Fallback: R10 single kernel (ws too small) =================
__global__ __launch_bounds__(256, 2)
void lstm_fused(const float* __restrict__ x, const float* __restrict__ W_ih,
                const float* __restrict__ W_hh, const float* __restrict__ b_ih,
                const float* __restrict__ b_hh, const float* __restrict__ ln_g,
                const float* __restrict__ ln_b, const float* __restrict__ W1,
                const float* __restrict__ b1, const float* __restrict__ W2,
                const float* __restrict__ b2, const float* __restrict__ Wo,
                const float* __restrict__ bo, const float* __restrict__ log_thr,
                float* __restrict__ out) {
    __shared__ float s_ring[CH][RS];
    __shared__ __align__(16) float s_h[2][HS];
    __shared__ __align__(16) float s_x[CH][20];
    __shared__ __align__(16) float s_W1[HH * HH];
    __shared__ __align__(16) float s_W2[HH * HH];
    __shared__ float s_lng[HH], s_lnb[HH], s_Wo[HH], s_b1[HH], s_b2[HH];
    __shared__ float s_part[256];

    const int tid = threadIdx.x;
    const int b = blockIdx.x;
    for (int i = tid; i < HH * HH; i += 256) { s_W1[i] = W1[i]; s_W2[i] = W2[i]; }
    if (tid < HH) {
        s_lng[tid] = ln_g[tid]; s_lnb[tid] = ln_b[tid]; s_Wo[tid] = Wo[tid];
        s_b1[tid] = b1[tid]; s_b2[tid] = b2[tid];
    }
    if (tid < HS) { s_h[0][tid] = 0.0f; s_h[1][tid] = 0.0f; }
    const float bo0 = bo[0];
    const float thrv = expf(log_thr[0]);
    const bool isGate = tid < 4 * HH;
    const int g = tid & 3, u = tid >> 2;
    const int grow = g * HH + u;
    const float mulk = (g == 2) ? 2.0f : 1.0f;
    float wih[DD], whh[HH], bsum = 0.0f;
    if (isGate) {
#pragma unroll
        for (int d = 0; d < DD; ++d) wih[d] = W_ih[grow * DD + d];
        const float4* wr = (const float4*)&W_hh[grow * HH];
#pragma unroll
        for (int q = 0; q < 10; ++q) {
            float4 f = wr[q];
            whh[4*q] = f.x; whh[4*q+1] = f.y; whh[4*q+2] = f.z; whh[4*q+3] = f.w;
        }
        bsum = b_ih[grow] + b_hh[grow];
    }
    float cc = 0.0f, hh = 0.0f;
    const int i0 = tid, i1 = tid + 256, i2 = tid + 512;
    const int st0 = i0 / DD, d0 = i0 % DD;
    const int st1 = i1 / DD, d1 = i1 % DD;
    const int st2 = i2 / DD, d2 = i2 % DD;
    float xr0 = 0.f, xr1 = 0.f, xr2 = 0.f;
    {
        const float* xp = x + (size_t)b * SS * DD;
        xr0 = xp[i0]; xr1 = xp[i1];
        if (i2 < CH * DD) xr2 = xp[i2];
    }
    __syncthreads();
    for (int ch = 0; ch < NCH; ++ch) {
        s_x[st0][d0] = xr0; s_x[st1][d1] = xr1;
        if (i2 < CH * DD) s_x[st2][d2] = xr2;
        if (ch + 1 < NCH) {
            const float* xp = x + ((size_t)b * SS + (size_t)(ch + 1) * CH) * DD;
            xr0 = xp[i0]; xr1 = xp[i1];
            if (i2 < CH * DD) xr2 = xp[i2];
        }
        __syncthreads();
        for (int t = 0; t < CH; ++t) {
            if (isGate) {
                const float4* h4 = (const float4*)s_h[t & 1];
                const float4* x4 = (const float4*)&s_x[t][0];
                float a0 = bsum, a1 = 0.f, a2 = 0.f, a3 = 0.f;
                float4 xa = x4[0], xb = x4[1], xc = x4[2], xd = x4[3], xe = x4[4];
                a0 = fmaf(xa.x, wih[0], a0);  a1 = fmaf(xa.y, wih[1], a1);
                a2 = fmaf(xa.z, wih[2], a2);  a3 = fmaf(xa.w, wih[3], a3);
                a0 = fmaf(xb.x, wih[4], a0);  a1 = fmaf(xb.y, wih[5], a1);
                a2 = fmaf(xb.z, wih[6], a2);  a3 = fmaf(xb.w, wih[7], a3);
                a0 = fmaf(xc.x, wih[8], a0);  a1 = fmaf(xc.y, wih[9], a1);
                a2 = fmaf(xc.z, wih[10], a2); a3 = fmaf(xc.w, wih[11], a3);
                a0 = fmaf(xd.x, wih[12], a0); a1 = fmaf(xd.y, wih[13], a1);
                a2 = fmaf(xd.z, wih[14], a2); a3 = fmaf(xd.w, wih[15], a3);
                a0 = fmaf(xe.x, wih[16], a0); a1 = fmaf(xe.y, wih[17], a1);
                a2 = fmaf(xe.z, wih[18], a2);
#pragma unroll
                for (int q = 0; q < 10; ++q) {
                    float4 f = h4[q];
                    a0 = fmaf(f.x, whh[4*q+0], a0);
                    a1 = fmaf(f.y, whh[4*q+1], a1);
                    a2 = fmaf(f.z, whh[4*q+2], a2);
                    a3 = fmaf(f.w, whh[4*q+3], a3);
                }
                float acc = (a0 + a1) + (a2 + a3);
                float av = gate_act(acc, mulk);
                float bv = __shfl_xor(av, 1);
                float cv = __shfl_xor(av, 2);
                float dv = __shfl_xor(bv, 2);
                if (g == 0) {
                    cc = fmaf(bv, cc, av * cv);
                    hh = dv * tanh_fast(cc);
                    s_h[(t + 1) & 1][u] = hh;
                    s_ring[t][u] = hh;
                }
            }
            __syncthreads();
        }
        {
            const int st = tid & 31;
            const int q8 = tid >> 5;
            float hv[HH];
#pragma unroll
            for (int k = 0; k < HH; ++k) hv[k] = s_ring[st][k];
            float m0 = 0.f, m1 = 0.f, q0 = 0.f, q1 = 0.f;
#pragma unroll
            for (int k = 0; k < HH; k += 2) {
                m0 += hv[k]; m1 += hv[k + 1];
                q0 = fmaf(hv[k], hv[k], q0); q1 = fmaf(hv[k + 1], hv[k + 1], q1);
            }
            float mu = (m0 + m1) * (1.0f / HH);
            float var = (q0 + q1) * (1.0f / HH) - mu * mu;
            float inv = 1.0f / sqrtf(var + 1e-5f);
#pragma unroll
            for (int k = 0; k < HH; ++k)
                hv[k] = fmaf((hv[k] - mu) * inv, s_lng[k], s_lnb[k]);
            float part = 0.f;
#pragma unroll
            for (int k = 0; k < HH; ++k)
                part = fmaf(sigm_fast(hv[k]), s_Wo[k], part);
            if (q8 != 0) part = 0.f;
            __syncthreads();
            float r1v[5];
#pragma unroll
            for (int jj = 0; jj < 5; ++jj) {
                int j = q8 * 5 + jj;
                const float4* wr = (const float4*)&s_W1[j * HH];
                float a0 = s_b1[j], a1 = 0.f;
#pragma unroll
                for (int q = 0; q < 10; ++q) {
                    float4 w4 = wr[q];
                    a0 = fmaf(w4.x, hv[4*q+0], a0); a1 = fmaf(w4.y, hv[4*q+1], a1);
                    a0 = fmaf(w4.z, hv[4*q+2], a0); a1 = fmaf(w4.w, hv[4*q+3], a1);
                }
                r1v[jj] = tanh_fast(a0 + a1);
                s_ring[st][j] = r1v[jj];
            }
            __syncthreads();
            float rr[HH];
#pragma unroll
            for (int k = 0; k < HH; ++k) rr[k] = s_ring[st][k];
#pragma unroll
            for (int jj = 0; jj < 5; ++jj) {
                int j = q8 * 5 + jj;
                const float4* wr = (const float4*)&s_W2[j * HH];
                float a0 = s_b2[j], a1 = 0.f;
#pragma unroll
                for (int q = 0; q < 10; ++q) {
                    float4 w4 = wr[q];
                    a0 = fmaf(w4.x, rr[4*q+0], a0); a1 = fmaf(w4.y, rr[4*q+1], a1);
                    a0 = fmaf(w4.z, rr[4*q+2], a0); a1 = fmaf(w4.w, rr[4*q+3], a1);
                }
                float r2 = tanh_fast(a0 + a1);
                part = fmaf(r2, s_Wo[j], part);
            }
            s_part[tid] = part;
            __syncthreads();
            if (tid < CH) {
                float tot = bo0;
#pragma unroll
                for (int qq = 0; qq < 8; ++qq) tot += s_part[tid + 32 * qq];
                float raw = tanh_fast(tot);
                float sg = (fabsf(raw) >= thrv) ? raw : 0.0f;
                out[(size_t)b * SS + (size_t)ch * CH + tid] = sg;
            }
        }
    }
    if (isGate && g == 0) {
        out[(size_t)BB * SS + (size_t)b * HH + u] = hh;
        out[(size_t)BB * SS + (size_t)BB * HH + (size_t)b * HH + u] = cc;
    }
    if (b == 0 && tid == 0) {
        out[(size_t)BB * SS + 2 * (size_t)BB * HH] = thrv;
    }
}

extern "C" void kernel_launch(void* const* d_in, const int* in_sizes, int n_in,
                              void* d_out, int out_size, void* d_ws, size_t ws_size,
                              hipStream_t stream) {
    const float* x    = (const float*)d_in[0];
    const float* W_ih = (const float*)d_in[1];
    const float* W_hh = (const float*)d_in[2];
    const float* b_ih = (const float*)d_in[3];
    const float* b_hh = (const float*)d_in[4];
    const float* ln_g = (const float*)d_in[5];
    const float* ln_b = (const float*)d_in[6];
    const float* W1   = (const float*)d_in[7];
    const float* b1   = (const float*)d_in[8];
    const float* W2   = (const float*)d_in[9];
    const float* b2   = (const float*)d_in[10];
    const float* Wo   = (const float*)d_in[11];
    const float* bo   = (const float*)d_in[12];
    const float* lt   = (const float*)d_in[13];
    float* out = (float*)d_out;

    const size_t need = (size_t)BB * SS * HH * sizeof(float);   // 168 MB h history
    if (ws_size >= need) {
        float* hist = (float*)d_ws;
        lstm_seq<<<dim3(BB), dim3(192), 0, stream>>>(
            x, W_ih, W_hh, b_ih, b_hh, lt, hist, out);
        post_mlp<<<dim3(BB * SS / 256), dim3(256), 0, stream>>>(
            hist, ln_g, ln_b, W1, b1, W2, b2, Wo, bo, lt, out);
    } else {
        lstm_fused<<<dim3(BB), dim3(256), 0, stream>>>(
            x, W_ih, W_hh, b_ih, b_hh, ln_g, ln_b, W1, b1, W2, b2, Wo, bo, lt, out);
    }
}